// Round 5
// baseline (855.332 us; speedup 1.0000x reference)
//
#include <hip/hip_runtime.h>
#include <stdint.h>

#define THREADS 256

typedef short bf16x8 __attribute__((ext_vector_type(8)));
typedef float f32x4 __attribute__((ext_vector_type(4)));
typedef unsigned uint2_ __attribute__((ext_vector_type(2)));
typedef unsigned short ushort4_ __attribute__((ext_vector_type(4)));

__device__ __forceinline__ unsigned short f2bf(float v) {
  unsigned u = __builtin_bit_cast(unsigned, v);
  u = (u + 0x7fff + ((u >> 16) & 1)) >> 16;
  return (unsigned short)u;
}
__device__ __forceinline__ float bf2f(unsigned short h) {
  return __builtin_bit_cast(float, (unsigned)h << 16);
}
__device__ __forceinline__ float fast_tanh(float x) {
  return 1.f - 2.f / (__expf(2.f * x) + 1.f);
}

// ---------------------------------------------------------------------------
// conv1 fused: x (NCHW f32, one sample per block) -> out (29*29, Bc, 32) bf16.
// Stage sample into LDS as bf16 (coalesced float4 reads), then each thread
// owns output positions: 45-tap window in VGPRs, wave-uniform weights
// (scalar loads), 4 parallel FMA chains, one 64B line store per pos.
// ---------------------------------------------------------------------------
__global__ void __launch_bounds__(256) conv1_direct(
    const float* __restrict__ x, const float* __restrict__ w,
    const float* __restrict__ bias, unsigned short* __restrict__ out, int Bc,
    int bstart) {
  constexpr int CI = 5, CO = 32, IH = 60, IW = 60, OH = 29, OW = 29, KS = 3, ST = 2;
  constexpr int NPIX = CI * IH * IW;  // 18000

  __shared__ unsigned short xs[NPIX];  // 36 KB

  const int tid = threadIdx.x;
  const int b = blockIdx.x;  // sample within chunk
  const float* xp = x + (size_t)(bstart + b) * NPIX;

  // stage: 4500 float4 -> ushort4 in LDS
  for (int i = tid; i < NPIX / 4; i += 256) {
    float4 v = ((const float4*)xp)[i];
    ushort4_ o;
    o[0] = f2bf(v.x);
    o[1] = f2bf(v.y);
    o[2] = f2bf(v.z);
    o[3] = f2bf(v.w);
    ((ushort4_*)xs)[i] = o;
  }

  float bias32[32];
#pragma unroll
  for (int co = 0; co < 32; co++) bias32[co] = bias[co];

  __syncthreads();

  for (int p = tid; p < OH * OW; p += 256) {
    const int oh = p / OW, ow = p % OW;
    const int ih0 = oh * ST, iw0 = ow * ST;

    float xv[45];
#pragma unroll
    for (int ci = 0; ci < CI; ci++)
#pragma unroll
      for (int kh = 0; kh < KS; kh++)
#pragma unroll
        for (int kw = 0; kw < KS; kw++)
          xv[(ci * KS + kh) * KS + kw] =
              bf2f(xs[ci * (IH * IW) + (ih0 + kh) * IW + iw0 + kw]);

    unsigned short* op = out + ((size_t)p * Bc + b) * CO;
#pragma unroll
    for (int cq = 0; cq < 8; cq++) {
      float a0 = bias32[cq * 4], a1 = bias32[cq * 4 + 1], a2 = bias32[cq * 4 + 2],
            a3 = bias32[cq * 4 + 3];
      const float* w0 = w + (cq * 4 + 0) * 45;
      const float* w1 = w + (cq * 4 + 1) * 45;
      const float* w2 = w + (cq * 4 + 2) * 45;
      const float* w3 = w + (cq * 4 + 3) * 45;
#pragma unroll
      for (int t = 0; t < 45; t++) {
        const float v = xv[t];
        a0 = fmaf(v, w0[t], a0);
        a1 = fmaf(v, w1[t], a1);
        a2 = fmaf(v, w2[t], a2);
        a3 = fmaf(v, w3[t], a3);
      }
      ushort4_ o;
      o[0] = f2bf(fast_tanh(a0));
      o[1] = f2bf(fast_tanh(a1));
      o[2] = f2bf(fast_tanh(a2));
      o[3] = f2bf(fast_tanh(a3));
      *(ushort4_*)(op + cq * 4) = o;
    }
  }
}

// ---------------------------------------------------------------------------
// Weight pre-pack into MFMA A-fragment order (bf16).
// dst wp: flat[pos][s][mt][lane][e], value = W[co=mt*16+(lane&15)]
//                                          [k = s*32 + (lane>>4)*8 + e]
// k-order: k = (kh*KS+kw)*CI + ci  (ci innermost).
// ---------------------------------------------------------------------------
template <int CI, int KS>
__global__ void __launch_bounds__(THREADS) pack_w(const float* __restrict__ w,
                                                  unsigned short* __restrict__ wp,
                                                  int npos) {
  constexpr int K = CI * KS * KS;
  constexpr int S = K / 32;
  int idx = blockIdx.x * THREADS + threadIdx.x;
  int total = npos * S * 2048;
  if (idx >= total) return;
  int e = idx & 7;
  int lane = (idx >> 3) & 63;
  int mt = (idx >> 9) & 3;
  int rest = idx >> 11;  // pos*S + s
  int s = rest % S, pos = rest / S;
  int co = mt * 16 + (lane & 15);
  int k = s * 32 + (lane >> 4) * 8 + e;
  int tap = k / CI, ci = k % CI;
  int kh = tap / KS, kw = tap % KS;
  float v = w[((((size_t)pos * 64 + co) * CI + ci) * KS + kh) * KS + kw];
  wp[idx] = f2bf(v);
}

// ---------------------------------------------------------------------------
// MFMA conv (dense or locally-connected), bf16 in/out, fp32 accum, tanh.
// X: (IH*IW, Bc, CI) bf16   Wp: packed   Y: (OH*OW, Bc, 64) bf16
// Block: 256 thr = 4 waves; one output position x 64 co x 128 batch.
// ---------------------------------------------------------------------------
template <int CI, int IH, int IW, int OH, int OW, int KS, int ST, bool LOCAL>
__global__ void __launch_bounds__(256) conv_mfma(
    const unsigned short* __restrict__ X, const unsigned short* __restrict__ Wp,
    const float* __restrict__ bias, unsigned short* __restrict__ Y, int Bc) {
  constexpr int K = CI * KS * KS;
  constexpr int S = K / 32;
  constexpr int NPOS = OH * OW;

  const int tid = threadIdx.x;
  const int lane = tid & 63;
  const int wu = tid >> 6;
  const int n = lane & 15, g = lane >> 4;

  const int pos = blockIdx.x % NPOS;
  const int btile = blockIdx.x / NPOS;
  const int oh = pos / OW, ow = pos % OW;
  const int b0 = btile * 128 + wu * 32;

  const unsigned short* Wpp = Wp + (LOCAL ? (size_t)pos * (S * 2048) : 0);

  f32x4 acc[4][2] = {};

  const int bA = b0 + n;
#pragma unroll 2
  for (int s = 0; s < S; s++) {
    const int tap = (s * 32) / CI;
    const int ci0 = (s * 32) % CI + g * 8;
    const int kh = tap / KS, kw = tap % KS;
    const int pin = (oh * ST + kh) * IW + (ow * ST + kw);
    const unsigned short* xb = X + ((size_t)pin * Bc + bA) * CI + ci0;
    bf16x8 bfr[2];
    bfr[0] = *(const bf16x8*)xb;
    bfr[1] = *(const bf16x8*)(xb + 16 * CI);
    bf16x8 af[4];
#pragma unroll
    for (int mt = 0; mt < 4; mt++)
      af[mt] = *(const bf16x8*)(Wpp + ((size_t)((s * 4 + mt) * 64 + lane) << 3));
#pragma unroll
    for (int mt = 0; mt < 4; mt++)
#pragma unroll
      for (int nf = 0; nf < 2; nf++)
        acc[mt][nf] =
            __builtin_amdgcn_mfma_f32_16x16x32_bf16(af[mt], bfr[nf], acc[mt][nf], 0, 0, 0);
  }

  // epilogue: D col=lane&15 (batch), row=(lane>>4)*4+reg (co)
#pragma unroll
  for (int mt = 0; mt < 4; mt++) {
#pragma unroll
    for (int nf = 0; nf < 2; nf++) {
      unsigned short o[4];
#pragma unroll
      for (int r = 0; r < 4; r++) {
        const int co = mt * 16 + g * 4 + r;
        const float bv = LOCAL ? bias[pos * 64 + co] : bias[co];
        o[r] = f2bf(fast_tanh(acc[mt][nf][r] + bv));
      }
      const int b = b0 + nf * 16 + n;
      uint2_ pk;
      pk[0] = (unsigned)o[0] | ((unsigned)o[1] << 16);
      pk[1] = (unsigned)o[2] | ((unsigned)o[3] << 16);
      *(uint2_*)(Y + ((size_t)pos * Bc + b) * 64 + mt * 16 + g * 4) = pk;
    }
  }
}

// ---------------------------------------------------------------------------
// Head: h5 (9, Bc, 64) bf16; f = co*9 + pos. concat info(8), linear, softmax.
// ---------------------------------------------------------------------------
__global__ void head_k(const unsigned short* __restrict__ h5,
                       const float* __restrict__ info, const float* __restrict__ hw,
                       const float* __restrict__ hb, float* __restrict__ out, int Bc,
                       int bstart) {
  int b = blockIdx.x * THREADS + threadIdx.x;
  if (b >= Bc) return;
  float l0 = hb[0], l1 = hb[1];
  for (int pos = 0; pos < 9; pos++) {
#pragma unroll
    for (int co = 0; co < 64; co++) {
      float v = bf2f(h5[((size_t)pos * Bc + b) * 64 + co]);
      int f = co * 9 + pos;
      l0 = fmaf(v, hw[f], l0);
      l1 = fmaf(v, hw[584 + f], l1);
    }
  }
#pragma unroll
  for (int k = 0; k < 8; k++) {
    float v = info[(size_t)(bstart + b) * 8 + k];
    l0 = fmaf(v, hw[576 + k], l0);
    l1 = fmaf(v, hw[584 + 576 + k], l1);
  }
  float m = fmaxf(l0, l1);
  float e0 = __expf(l0 - m), e1 = __expf(l1 - m);
  float s = e0 + e1;
  out[(size_t)(bstart + b) * 2 + 0] = e0 / s;
  out[(size_t)(bstart + b) * 2 + 1] = e1 / s;
}

// ---------------------------------------------------------------------------

extern "C" void kernel_launch(void* const* d_in, const int* in_sizes, int n_in,
                              void* d_out, int out_size, void* d_ws, size_t ws_size,
                              hipStream_t stream) {
  const float* x = (const float*)d_in[0];
  const float* info = (const float*)d_in[1];
  const float* w1 = (const float*)d_in[2];
  const float* b1 = (const float*)d_in[3];
  const float* w2a = (const float*)d_in[4];
  const float* b2a = (const float*)d_in[5];
  const float* w2b = (const float*)d_in[6];
  const float* b2b = (const float*)d_in[7];
  const float* lw3 = (const float*)d_in[8];
  const float* lb3 = (const float*)d_in[9];
  const float* lw4 = (const float*)d_in[10];
  const float* lb4 = (const float*)d_in[11];
  const float* lw5 = (const float*)d_in[12];
  const float* lb5 = (const float*)d_in[13];
  const float* hw = (const float*)d_in[14];
  const float* hb = (const float*)d_in[15];
  float* out = (float*)d_out;

  const int B = in_sizes[0] / 18000;  // 2048

  // packed weights at ws start (S = K/32, each step = 2048 ushorts)
  const size_t SZ2A = 9ull * 2048, SZ2B = 18ull * 2048, SZ3 = 81ull * 50 * 2048,
               SZ4 = 25ull * 50 * 2048, SZ5 = 9ull * 18 * 2048;
  unsigned short* wp2a = (unsigned short*)d_ws;
  unsigned short* wp2b = wp2a + SZ2A;
  unsigned short* wp3 = wp2b + SZ2B;
  unsigned short* wp4 = wp3 + SZ3;
  unsigned short* wp5 = wp4 + SZ4;
  size_t wp_bytes = (SZ2A + SZ2B + SZ3 + SZ4 + SZ5) * 2;
  wp_bytes = (wp_bytes + 255) & ~(size_t)255;

  // per-sample chunk buffers: bufA bf16 53824B, bufB bf16 93312B
  const size_t per_sample = 53824 + 93312;
  int Bc = B;
  while (Bc > 256 && wp_bytes + (size_t)Bc * per_sample + 4096 > ws_size) Bc >>= 1;
  const int nbt = Bc / 128;

  unsigned short* bufA = (unsigned short*)((char*)d_ws + wp_bytes);
  unsigned short* bufB = (unsigned short*)((char*)d_ws + wp_bytes + (size_t)Bc * 53824);

  // one-time weight packing (deterministic each launch)
  hipLaunchKernelGGL((pack_w<32, 3>), dim3((SZ2A + 255) / 256), dim3(THREADS), 0, stream,
                     w2a, wp2a, 1);
  hipLaunchKernelGGL((pack_w<64, 3>), dim3((SZ2B + 255) / 256), dim3(THREADS), 0, stream,
                     w2b, wp2b, 1);
  hipLaunchKernelGGL((pack_w<64, 5>), dim3((SZ3 + 255) / 256), dim3(THREADS), 0, stream,
                     lw3, wp3, 81);
  hipLaunchKernelGGL((pack_w<64, 5>), dim3((SZ4 + 255) / 256), dim3(THREADS), 0, stream,
                     lw4, wp4, 25);
  hipLaunchKernelGGL((pack_w<64, 3>), dim3((SZ5 + 255) / 256), dim3(THREADS), 0, stream,
                     lw5, wp5, 9);

  const int nchunks = B / Bc;
  for (int c = 0; c < nchunks; c++) {
    const int bstart = c * Bc;

    // conv1 fused (transpose+cast+conv): 5->32, 60x60 -> 29x29, k3 s2
    hipLaunchKernelGGL(conv1_direct, dim3(Bc), dim3(256), 0, stream, x, w1, b1, bufA, Bc,
                       bstart);
    // conv2a: 32->64, 29x29 -> 27x27, k3 s1
    hipLaunchKernelGGL((conv_mfma<32, 29, 29, 27, 27, 3, 1, false>),
                       dim3(729 * nbt), dim3(256), 0, stream, bufA, wp2a, b2a, bufB, Bc);
    // conv2b: 64->64, 27x27 -> 13x13, k3 s2
    hipLaunchKernelGGL((conv_mfma<64, 27, 27, 13, 13, 3, 2, false>),
                       dim3(169 * nbt), dim3(256), 0, stream, bufB, wp2b, b2b, bufA, Bc);
    // local3: 64->64, 13x13 -> 9x9, k5
    hipLaunchKernelGGL((conv_mfma<64, 13, 13, 9, 9, 5, 1, true>),
                       dim3(81 * nbt), dim3(256), 0, stream, bufA, wp3, lb3, bufB, Bc);
    // local4: 64->64, 9x9 -> 5x5, k5
    hipLaunchKernelGGL((conv_mfma<64, 9, 9, 5, 5, 5, 1, true>),
                       dim3(25 * nbt), dim3(256), 0, stream, bufB, wp4, lb4, bufA, Bc);
    // local5: 64->64, 5x5 -> 3x3, k3
    hipLaunchKernelGGL((conv_mfma<64, 5, 5, 3, 3, 3, 1, true>),
                       dim3(9 * nbt), dim3(256), 0, stream, bufA, wp5, lb5, bufB, Bc);
    // head
    hipLaunchKernelGGL(head_k, dim3((Bc + THREADS - 1) / THREADS), dim3(THREADS), 0,
                       stream, bufB, info, hw, hb, out, Bc, bstart);
  }
}

// Round 6
// 599.179 us; speedup vs baseline: 1.4275x; 1.4275x over previous
//
#include <hip/hip_runtime.h>
#include <stdint.h>

#define THREADS 256

typedef short bf16x8 __attribute__((ext_vector_type(8)));
typedef float f32x4 __attribute__((ext_vector_type(4)));
typedef unsigned uint2_ __attribute__((ext_vector_type(2)));
typedef unsigned short ushort4_ __attribute__((ext_vector_type(4)));

#define GPTR(x) ((const __attribute__((address_space(1))) void*)(x))
#define LPTR(x) ((__attribute__((address_space(3))) void*)(x))

__device__ __forceinline__ unsigned short f2bf(float v) {
  unsigned u = __builtin_bit_cast(unsigned, v);
  u = (u + 0x7fff + ((u >> 16) & 1)) >> 16;
  return (unsigned short)u;
}
__device__ __forceinline__ float bf2f(unsigned short h) {
  return __builtin_bit_cast(float, (unsigned)h << 16);
}
__device__ __forceinline__ float fast_tanh(float x) {
  return 1.f - 2.f / (__expf(2.f * x) + 1.f);
}

// ---------------------------------------------------------------------------
// conv1 fused: x NCHW f32 -> out (29*29, Bc, 32) bf16, k3 s2, tanh.
// 4 blocks per sample (8 oh-rows each). LDS 10.2KB; each thread = 1 position.
// ---------------------------------------------------------------------------
__global__ void __launch_bounds__(256) conv1_direct(
    const float* __restrict__ x, const float* __restrict__ w,
    const float* __restrict__ bias, unsigned short* __restrict__ out, int Bc,
    int bstart) {
  constexpr int CI = 5, CO = 32, IH = 60, IW = 60, OH = 29, OW = 29;
  constexpr int RB = 8, NRB = 4;  // oh rows per block, blocks per sample

  __shared__ unsigned short xs[CI * 17 * 60];  // 10200 B

  const int tid = threadIdx.x;
  const int b = blockIdx.x / NRB;
  const int qb = blockIdx.x % NRB;
  const int oh0 = qb * RB;
  const int rows = min(RB, OH - oh0);  // 8,8,8,5
  const int ih0 = oh0 * 2;
  const int ihn = rows * 2 + 1;  // 17 or 11

  const float* xp = x + (size_t)(bstart + b) * (CI * IH * IW);

  // stage [ci][ih0..ih0+ihn)[0..60) as bf16; rows are float4-aligned (240B)
  const int nf4 = CI * ihn * 15;
  for (int i = tid; i < nf4; i += 256) {
    int col = i % 15;
    int row = i / 15;  // ci*ihn + r
    int ci = row / ihn, r = row % ihn;
    float4 v = ((const float4*)xp)[(ci * IH + ih0 + r) * 15 + col];
    ushort4_ o;
    o[0] = f2bf(v.x);
    o[1] = f2bf(v.y);
    o[2] = f2bf(v.z);
    o[3] = f2bf(v.w);
    ((ushort4_*)xs)[row * 15 + col] = o;
  }
  __syncthreads();

  if (tid >= rows * OW) return;
  const int r = tid / OW, c = tid % OW;

  float xv[45];
#pragma unroll
  for (int ci = 0; ci < CI; ci++)
#pragma unroll
    for (int kh = 0; kh < 3; kh++)
#pragma unroll
      for (int kw = 0; kw < 3; kw++)
        xv[(ci * 3 + kh) * 3 + kw] = bf2f(xs[(ci * ihn + r * 2 + kh) * 60 + c * 2 + kw]);

  const int p = (oh0 + r) * OW + c;
  unsigned short* op = out + ((size_t)p * Bc + b) * CO;
#pragma unroll
  for (int cq = 0; cq < 8; cq++) {
    float a0 = bias[cq * 4], a1 = bias[cq * 4 + 1], a2 = bias[cq * 4 + 2],
          a3 = bias[cq * 4 + 3];
    const float* w0 = w + (cq * 4 + 0) * 45;
    const float* w1 = w + (cq * 4 + 1) * 45;
    const float* w2 = w + (cq * 4 + 2) * 45;
    const float* w3 = w + (cq * 4 + 3) * 45;
#pragma unroll
    for (int t = 0; t < 45; t++) {
      const float v = xv[t];
      a0 = fmaf(v, w0[t], a0);
      a1 = fmaf(v, w1[t], a1);
      a2 = fmaf(v, w2[t], a2);
      a3 = fmaf(v, w3[t], a3);
    }
    ushort4_ o;
    o[0] = f2bf(fast_tanh(a0));
    o[1] = f2bf(fast_tanh(a1));
    o[2] = f2bf(fast_tanh(a2));
    o[3] = f2bf(fast_tanh(a3));
    *(ushort4_*)(op + cq * 4) = o;
  }
}

// ---------------------------------------------------------------------------
// Weight pre-pack into MFMA A-fragment order (bf16).
// dst wp: flat[pos][s][mt][lane][e], value = W[co=mt*16+(lane&15)]
//                                          [k = s*32 + (lane>>4)*8 + e]
// k-order: k = (kh*KS+kw)*CI + ci  (ci innermost).
// ---------------------------------------------------------------------------
template <int CI, int KS>
__global__ void __launch_bounds__(THREADS) pack_w(const float* __restrict__ w,
                                                  unsigned short* __restrict__ wp,
                                                  int npos) {
  constexpr int K = CI * KS * KS;
  constexpr int S = K / 32;
  int idx = blockIdx.x * THREADS + threadIdx.x;
  int total = npos * S * 2048;
  if (idx >= total) return;
  int e = idx & 7;
  int lane = (idx >> 3) & 63;
  int mt = (idx >> 9) & 3;
  int rest = idx >> 11;  // pos*S + s
  int s = rest % S, pos = rest / S;
  int co = mt * 16 + (lane & 15);
  int k = s * 32 + (lane >> 4) * 8 + e;
  int tap = k / CI, ci = k % CI;
  int kh = tap / KS, kw = tap % KS;
  float v = w[((((size_t)pos * 64 + co) * CI + ci) * KS + kh) * KS + kw];
  wp[idx] = f2bf(v);
}

// ---------------------------------------------------------------------------
// MFMA conv v2: bf16 in/out, fp32 accum, tanh.
// X: (IH*IW, Bc, CI)  Wp: packed  Y: (OH*OW, Bc, 64)
// Block: 4 waves = one pos x 64 co x 256 batch (wave: 64 batch, nf=4).
// A staged per K-step into double-buffered LDS (global_load_lds w16, linear),
// shared by all waves; B-frags direct 16B global loads (L2-resident).
// Bijective XCD swizzle keeps pos-adjacent blocks on one XCD's L2.
// ---------------------------------------------------------------------------
template <int CI, int IH, int IW, int OH, int OW, int KS, int ST, bool LOCAL>
__global__ void __launch_bounds__(256) conv_mfma(
    const unsigned short* __restrict__ X, const unsigned short* __restrict__ Wp,
    const float* __restrict__ bias, unsigned short* __restrict__ Y, int Bc) {
  constexpr int S = CI * KS * KS / 32;
  constexpr int NPOS = OH * OW;

  __shared__ unsigned short aT[2][2048];  // 8 KB double buffer

  const int tid = threadIdx.x;
  const int lane = tid & 63;
  const int wu = tid >> 6;
  const int n = lane & 15, g = lane >> 4;

  // bijective XCD-chunked swizzle (m204)
  int wg = blockIdx.x;
  {
    const int nwg = gridDim.x;
    const int q = nwg >> 3, rr = nwg & 7;
    const int xcd = wg & 7, l = wg >> 3;
    wg = (xcd < rr ? xcd * (q + 1) : rr * (q + 1) + (xcd - rr) * q) + l;
  }
  const int pos = wg % NPOS;
  const int btile = wg / NPOS;
  const int oh = pos / OW, ow = pos % OW;
  const int b0 = btile * 256 + wu * 64;

  const unsigned short* Wpp = Wp + (LOCAL ? (size_t)pos * (S * 2048) : 0);

  f32x4 acc[4][4] = {};

  const int bA = b0 + n;

  // prologue stage s=0
  __builtin_amdgcn_global_load_lds(GPTR(Wpp + tid * 8), LPTR(&aT[0][tid * 8]), 16, 0, 0);

  int buf = 0;
  for (int s = 0; s < S; s++) {
    __syncthreads();  // staged buf ready; previous reads of buf^1 done
    if (s + 1 < S)
      __builtin_amdgcn_global_load_lds(GPTR(Wpp + (s + 1) * 2048 + tid * 8),
                                       LPTR(&aT[buf ^ 1][tid * 8]), 16, 0, 0);

    const int tap = (s * 32) / CI;
    const int ci0 = (s * 32) % CI + g * 8;
    const int kh = tap / KS, kw = tap % KS;
    const int pin = (oh * ST + kh) * IW + (ow * ST + kw);
    const unsigned short* xb = X + ((size_t)pin * Bc + bA) * CI + ci0;

    bf16x8 bfr[4];
#pragma unroll
    for (int j = 0; j < 4; j++) bfr[j] = *(const bf16x8*)(xb + j * 16 * CI);

    bf16x8 af[4];
#pragma unroll
    for (int mt = 0; mt < 4; mt++)
      af[mt] = *(const bf16x8*)(&aT[buf][(mt * 64 + lane) * 8]);

#pragma unroll
    for (int mt = 0; mt < 4; mt++)
#pragma unroll
      for (int j = 0; j < 4; j++)
        acc[mt][j] =
            __builtin_amdgcn_mfma_f32_16x16x32_bf16(af[mt], bfr[j], acc[mt][j], 0, 0, 0);
    buf ^= 1;
  }

  // epilogue: D col=lane&15 (batch), row=(lane>>4)*4+reg (co)
#pragma unroll
  for (int mt = 0; mt < 4; mt++) {
#pragma unroll
    for (int j = 0; j < 4; j++) {
      unsigned short o[4];
#pragma unroll
      for (int r = 0; r < 4; r++) {
        const int co = mt * 16 + g * 4 + r;
        const float bv = LOCAL ? bias[pos * 64 + co] : bias[co];
        o[r] = f2bf(fast_tanh(acc[mt][j][r] + bv));
      }
      const int b = b0 + j * 16 + n;
      uint2_ pk;
      pk[0] = (unsigned)o[0] | ((unsigned)o[1] << 16);
      pk[1] = (unsigned)o[2] | ((unsigned)o[3] << 16);
      *(uint2_*)(Y + ((size_t)pos * Bc + b) * 64 + mt * 16 + g * 4) = pk;
    }
  }
}

// ---------------------------------------------------------------------------
// Head: h5 (9, Bc, 64) bf16; f = co*9 + pos. concat info(8), linear, softmax.
// ---------------------------------------------------------------------------
__global__ void head_k(const unsigned short* __restrict__ h5,
                       const float* __restrict__ info, const float* __restrict__ hw,
                       const float* __restrict__ hb, float* __restrict__ out, int Bc,
                       int bstart) {
  int b = blockIdx.x * THREADS + threadIdx.x;
  if (b >= Bc) return;
  float l0 = hb[0], l1 = hb[1];
  for (int pos = 0; pos < 9; pos++) {
#pragma unroll
    for (int cb = 0; cb < 8; cb++) {
      bf16x8 v8 = *(const bf16x8*)(h5 + ((size_t)pos * Bc + b) * 64 + cb * 8);
#pragma unroll
      for (int j = 0; j < 8; j++) {
        float v = bf2f((unsigned short)v8[j]);
        int f = (cb * 8 + j) * 9 + pos;
        l0 = fmaf(v, hw[f], l0);
        l1 = fmaf(v, hw[584 + f], l1);
      }
    }
  }
#pragma unroll
  for (int k = 0; k < 8; k++) {
    float v = info[(size_t)(bstart + b) * 8 + k];
    l0 = fmaf(v, hw[576 + k], l0);
    l1 = fmaf(v, hw[584 + 576 + k], l1);
  }
  float m = fmaxf(l0, l1);
  float e0 = __expf(l0 - m), e1 = __expf(l1 - m);
  float s = e0 + e1;
  out[(size_t)(bstart + b) * 2 + 0] = e0 / s;
  out[(size_t)(bstart + b) * 2 + 1] = e1 / s;
}

// ---------------------------------------------------------------------------

extern "C" void kernel_launch(void* const* d_in, const int* in_sizes, int n_in,
                              void* d_out, int out_size, void* d_ws, size_t ws_size,
                              hipStream_t stream) {
  const float* x = (const float*)d_in[0];
  const float* info = (const float*)d_in[1];
  const float* w1 = (const float*)d_in[2];
  const float* b1 = (const float*)d_in[3];
  const float* w2a = (const float*)d_in[4];
  const float* b2a = (const float*)d_in[5];
  const float* w2b = (const float*)d_in[6];
  const float* b2b = (const float*)d_in[7];
  const float* lw3 = (const float*)d_in[8];
  const float* lb3 = (const float*)d_in[9];
  const float* lw4 = (const float*)d_in[10];
  const float* lb4 = (const float*)d_in[11];
  const float* lw5 = (const float*)d_in[12];
  const float* lb5 = (const float*)d_in[13];
  const float* hw = (const float*)d_in[14];
  const float* hb = (const float*)d_in[15];
  float* out = (float*)d_out;

  const int B = in_sizes[0] / 18000;  // 2048

  // packed weights at ws start (S = K/32, each step = 2048 ushorts)
  const size_t SZ2A = 9ull * 2048, SZ2B = 18ull * 2048, SZ3 = 81ull * 50 * 2048,
               SZ4 = 25ull * 50 * 2048, SZ5 = 9ull * 18 * 2048;
  unsigned short* wp2a = (unsigned short*)d_ws;
  unsigned short* wp2b = wp2a + SZ2A;
  unsigned short* wp3 = wp2b + SZ2B;
  unsigned short* wp4 = wp3 + SZ3;
  unsigned short* wp5 = wp4 + SZ4;
  size_t wp_bytes = (SZ2A + SZ2B + SZ3 + SZ4 + SZ5) * 2;
  wp_bytes = (wp_bytes + 255) & ~(size_t)255;

  // per-sample chunk buffers: bufA bf16 53824B, bufB bf16 93312B
  const size_t per_sample = 53824 + 93312;
  int Bc = B;
  while (Bc > 256 && wp_bytes + (size_t)Bc * per_sample + 4096 > ws_size) Bc >>= 1;
  const int nbt = Bc / 256;

  unsigned short* bufA = (unsigned short*)((char*)d_ws + wp_bytes);
  unsigned short* bufB = (unsigned short*)((char*)d_ws + wp_bytes + (size_t)Bc * 53824);

  // one-time weight packing (deterministic each launch)
  hipLaunchKernelGGL((pack_w<32, 3>), dim3((SZ2A + 255) / 256), dim3(THREADS), 0, stream,
                     w2a, wp2a, 1);
  hipLaunchKernelGGL((pack_w<64, 3>), dim3((SZ2B + 255) / 256), dim3(THREADS), 0, stream,
                     w2b, wp2b, 1);
  hipLaunchKernelGGL((pack_w<64, 5>), dim3((SZ3 + 255) / 256), dim3(THREADS), 0, stream,
                     lw3, wp3, 81);
  hipLaunchKernelGGL((pack_w<64, 5>), dim3((SZ4 + 255) / 256), dim3(THREADS), 0, stream,
                     lw4, wp4, 25);
  hipLaunchKernelGGL((pack_w<64, 3>), dim3((SZ5 + 255) / 256), dim3(THREADS), 0, stream,
                     lw5, wp5, 9);

  const int nchunks = B / Bc;
  for (int c = 0; c < nchunks; c++) {
    const int bstart = c * Bc;

    // conv1 fused: 5->32, 60x60 -> 29x29, k3 s2; 4 blocks/sample
    hipLaunchKernelGGL(conv1_direct, dim3(Bc * 4), dim3(256), 0, stream, x, w1, b1,
                       bufA, Bc, bstart);
    // conv2a: 32->64, 29x29 -> 27x27, k3 s1
    hipLaunchKernelGGL((conv_mfma<32, 29, 29, 27, 27, 3, 1, false>),
                       dim3(729 * nbt), dim3(256), 0, stream, bufA, wp2a, b2a, bufB, Bc);
    // conv2b: 64->64, 27x27 -> 13x13, k3 s2
    hipLaunchKernelGGL((conv_mfma<64, 27, 27, 13, 13, 3, 2, false>),
                       dim3(169 * nbt), dim3(256), 0, stream, bufB, wp2b, b2b, bufA, Bc);
    // local3: 64->64, 13x13 -> 9x9, k5
    hipLaunchKernelGGL((conv_mfma<64, 13, 13, 9, 9, 5, 1, true>),
                       dim3(81 * nbt), dim3(256), 0, stream, bufA, wp3, lb3, bufB, Bc);
    // local4: 64->64, 9x9 -> 5x5, k5
    hipLaunchKernelGGL((conv_mfma<64, 9, 9, 5, 5, 5, 1, true>),
                       dim3(25 * nbt), dim3(256), 0, stream, bufB, wp4, lb4, bufA, Bc);
    // local5: 64->64, 5x5 -> 3x3, k3
    hipLaunchKernelGGL((conv_mfma<64, 5, 5, 3, 3, 3, 1, true>),
                       dim3(9 * nbt), dim3(256), 0, stream, bufA, wp5, lb5, bufB, Bc);
    // head
    hipLaunchKernelGGL(head_k, dim3((Bc + THREADS - 1) / THREADS), dim3(THREADS), 0,
                       stream, bufB, info, hw, hb, out, Bc, bstart);
  }
}

// Round 7
// 574.384 us; speedup vs baseline: 1.4891x; 1.0432x over previous
//
#include <hip/hip_runtime.h>
#include <stdint.h>

#define THREADS 256

typedef short bf16x8 __attribute__((ext_vector_type(8)));
typedef float f32x4 __attribute__((ext_vector_type(4)));
typedef unsigned uint2_ __attribute__((ext_vector_type(2)));
typedef unsigned short ushort4_ __attribute__((ext_vector_type(4)));

#define GPTR(x) ((const __attribute__((address_space(1))) void*)(x))
#define LPTR(x) ((__attribute__((address_space(3))) void*)(x))

__device__ __forceinline__ unsigned short f2bf(float v) {
  unsigned u = __builtin_bit_cast(unsigned, v);
  u = (u + 0x7fff + ((u >> 16) & 1)) >> 16;
  return (unsigned short)u;
}
__device__ __forceinline__ float bf2f(unsigned short h) {
  return __builtin_bit_cast(float, (unsigned)h << 16);
}
__device__ __forceinline__ float fast_tanh(float x) {
  return 1.f - 2.f / (__expf(2.f * x) + 1.f);
}

// ---------------------------------------------------------------------------
// w1 transpose: (32, 45) -> (45, 32) fp32, for wave-uniform dwordx16 loads.
// ---------------------------------------------------------------------------
__global__ void pack_w1t(const float* __restrict__ w1, float* __restrict__ w1t) {
  int idx = blockIdx.x * THREADS + threadIdx.x;
  if (idx >= 45 * 32) return;
  int t = idx >> 5, co = idx & 31;
  w1t[t * 32 + co] = w1[co * 45 + t];
}

// ---------------------------------------------------------------------------
// conv1 fused: x NCHW f32 -> out (29*29, Bc, 32) bf16, k3 s2, tanh.
// 4 blocks/sample (8 oh-rows). acc[32] in VGPRs; each tap read from LDS ONCE
// and broadcast to all 32 channels; weights w1t[t][co] via scalar loads.
// ---------------------------------------------------------------------------
__global__ void __launch_bounds__(256) conv1_direct(
    const float* __restrict__ x, const float* __restrict__ w1t,
    const float* __restrict__ bias, unsigned short* __restrict__ out, int Bc,
    int bstart) {
  constexpr int CI = 5, CO = 32, IH = 60, IW = 60, OH = 29, OW = 29;
  constexpr int RB = 8, NRB = 4;

  __shared__ unsigned short xs[CI * 17 * 60];  // 10200 B

  const int tid = threadIdx.x;
  const int b = blockIdx.x / NRB;
  const int qb = blockIdx.x % NRB;
  const int oh0 = qb * RB;
  const int rows = min(RB, OH - oh0);  // 8,8,8,5
  const int ih0 = oh0 * 2;
  const int ihn = rows * 2 + 1;  // 17 or 11

  const float* xp = x + (size_t)(bstart + b) * (CI * IH * IW);

  const int nf4 = CI * ihn * 15;
  for (int i = tid; i < nf4; i += 256) {
    int col = i % 15;
    int row = i / 15;  // ci*ihn + r
    int ci = row / ihn, r = row % ihn;
    float4 v = ((const float4*)xp)[(ci * IH + ih0 + r) * 15 + col];
    ushort4_ o;
    o[0] = f2bf(v.x);
    o[1] = f2bf(v.y);
    o[2] = f2bf(v.z);
    o[3] = f2bf(v.w);
    ((ushort4_*)xs)[row * 15 + col] = o;
  }
  __syncthreads();

  if (tid >= rows * OW) return;
  const int r = tid / OW, c = tid % OW;
  const int base = (r * 2) * 60 + c * 2;
  const int cstr = ihn * 60;

  float acc[32];
#pragma unroll
  for (int co = 0; co < 32; co++) acc[co] = bias[co];

#pragma unroll
  for (int ci = 0; ci < CI; ci++)
#pragma unroll
    for (int kh = 0; kh < 3; kh++)
#pragma unroll
      for (int kw = 0; kw < 3; kw++) {
        const float v = bf2f(xs[ci * cstr + base + kh * 60 + kw]);
        const float* wt = w1t + ((ci * 3 + kh) * 3 + kw) * 32;
#pragma unroll
        for (int co = 0; co < 32; co++) acc[co] = fmaf(v, wt[co], acc[co]);
      }

  const int p = (oh0 + r) * OW + c;
  unsigned short* op = out + ((size_t)p * Bc + b) * CO;
#pragma unroll
  for (int cq = 0; cq < 4; cq++) {
    bf16x8 o;
#pragma unroll
    for (int j = 0; j < 8; j++) o[j] = (short)f2bf(fast_tanh(acc[cq * 8 + j]));
    *(bf16x8*)(op + cq * 8) = o;
  }
}

// ---------------------------------------------------------------------------
// Weight pre-pack into MFMA A-fragment order (bf16).
// dst wp: flat[pos][s][mt][lane][e], value = W[co=mt*16+(lane&15)]
//                                          [k = s*32 + (lane>>4)*8 + e]
// k-order: k = (kh*KS+kw)*CI + ci  (ci innermost).
// ---------------------------------------------------------------------------
template <int CI, int KS>
__global__ void __launch_bounds__(THREADS) pack_w(const float* __restrict__ w,
                                                  unsigned short* __restrict__ wp,
                                                  int npos) {
  constexpr int K = CI * KS * KS;
  constexpr int S = K / 32;
  int idx = blockIdx.x * THREADS + threadIdx.x;
  int total = npos * S * 2048;
  if (idx >= total) return;
  int e = idx & 7;
  int lane = (idx >> 3) & 63;
  int mt = (idx >> 9) & 3;
  int rest = idx >> 11;  // pos*S + s
  int s = rest % S, pos = rest / S;
  int co = mt * 16 + (lane & 15);
  int k = s * 32 + (lane >> 4) * 8 + e;
  int tap = k / CI, ci = k % CI;
  int kh = tap / KS, kw = tap % KS;
  float v = w[((((size_t)pos * 64 + co) * CI + ci) * KS + kh) * KS + kw];
  wp[idx] = f2bf(v);
}

// ---------------------------------------------------------------------------
// MFMA conv v3: bf16 in/out, fp32 accum, tanh. Batch-tile BT templated.
// X: (IH*IW, Bc, CI)  Wp: packed  Y: (OH*OW, Bc, 64)
// Block: 4 waves = one pos x 64 co x BT batch. Waves tile (co BW-groups x
// batch CW-groups): BT=256 -> waves split batch; BT=64 -> waves split co
// (small layers get 4x more blocks). A double-buffered in LDS via
// global_load_lds; B direct 16B global loads. Bijective XCD swizzle.
// ---------------------------------------------------------------------------
template <int CI, int IH, int IW, int OH, int OW, int KS, int ST, bool LOCAL, int BT>
__global__ void __launch_bounds__(256) conv_mfma(
    const unsigned short* __restrict__ X, const unsigned short* __restrict__ Wp,
    const float* __restrict__ bias, unsigned short* __restrict__ Y, int Bc) {
  constexpr int S = CI * KS * KS / 32;
  constexpr int NPOS = OH * OW;
  constexpr int BW = BT / 64;  // waves along batch
  constexpr int CW = 4 / BW;   // waves along co
  constexpr int MT = 4 / CW;   // 16-co tiles per wave

  __shared__ unsigned short aT[2][2048];  // 8 KB double buffer

  const int tid = threadIdx.x;
  const int lane = tid & 63;
  const int wu = tid >> 6;
  const int n = lane & 15, g = lane >> 4;
  const int bw = wu % BW, cw = wu / BW;

  // bijective XCD-chunked swizzle (m204)
  int wg = blockIdx.x;
  {
    const int nwg = gridDim.x;
    const int q = nwg >> 3, rr = nwg & 7;
    const int xcd = wg & 7, l = wg >> 3;
    wg = (xcd < rr ? xcd * (q + 1) : rr * (q + 1) + (xcd - rr) * q) + l;
  }
  const int pos = wg % NPOS;
  const int btile = wg / NPOS;
  const int oh = pos / OW, ow = pos % OW;
  const int b0 = btile * BT + bw * 64;

  const unsigned short* Wpp = Wp + (LOCAL ? (size_t)pos * (S * 2048) : 0);

  f32x4 acc[MT][4] = {};

  const int bA = b0 + n;

  __builtin_amdgcn_global_load_lds(GPTR(Wpp + tid * 8), LPTR(&aT[0][tid * 8]), 16, 0, 0);

  int buf = 0;
  for (int s = 0; s < S; s++) {
    __syncthreads();
    if (s + 1 < S)
      __builtin_amdgcn_global_load_lds(GPTR(Wpp + (s + 1) * 2048 + tid * 8),
                                       LPTR(&aT[buf ^ 1][tid * 8]), 16, 0, 0);

    const int tap = (s * 32) / CI;
    const int ci0 = (s * 32) % CI + g * 8;
    const int kh = tap / KS, kw = tap % KS;
    const int pin = (oh * ST + kh) * IW + (ow * ST + kw);
    const unsigned short* xb = X + ((size_t)pin * Bc + bA) * CI + ci0;

    bf16x8 bfr[4];
#pragma unroll
    for (int j = 0; j < 4; j++) bfr[j] = *(const bf16x8*)(xb + j * 16 * CI);

    bf16x8 af[MT];
#pragma unroll
    for (int mt = 0; mt < MT; mt++)
      af[mt] = *(const bf16x8*)(&aT[buf][((cw * MT + mt) * 64 + lane) * 8]);

#pragma unroll
    for (int mt = 0; mt < MT; mt++)
#pragma unroll
      for (int j = 0; j < 4; j++)
        acc[mt][j] =
            __builtin_amdgcn_mfma_f32_16x16x32_bf16(af[mt], bfr[j], acc[mt][j], 0, 0, 0);
    buf ^= 1;
  }

  // epilogue: D col=lane&15 (batch), row=(lane>>4)*4+reg (co)
#pragma unroll
  for (int mt = 0; mt < MT; mt++) {
#pragma unroll
    for (int j = 0; j < 4; j++) {
      unsigned short o[4];
#pragma unroll
      for (int r = 0; r < 4; r++) {
        const int co = (cw * MT + mt) * 16 + g * 4 + r;
        const float bv = LOCAL ? bias[pos * 64 + co] : bias[co];
        o[r] = f2bf(fast_tanh(acc[mt][j][r] + bv));
      }
      const int b = b0 + j * 16 + n;
      uint2_ pk;
      pk[0] = (unsigned)o[0] | ((unsigned)o[1] << 16);
      pk[1] = (unsigned)o[2] | ((unsigned)o[3] << 16);
      *(uint2_*)(Y + ((size_t)pos * Bc + b) * 64 + (cw * MT + mt) * 16 + g * 4) = pk;
    }
  }
}

// ---------------------------------------------------------------------------
// Head: h5 (9, Bc, 64) bf16; f = co*9 + pos. concat info(8), linear, softmax.
// ---------------------------------------------------------------------------
__global__ void head_k(const unsigned short* __restrict__ h5,
                       const float* __restrict__ info, const float* __restrict__ hw,
                       const float* __restrict__ hb, float* __restrict__ out, int Bc,
                       int bstart) {
  int b = blockIdx.x * THREADS + threadIdx.x;
  if (b >= Bc) return;
  float l0 = hb[0], l1 = hb[1];
  for (int pos = 0; pos < 9; pos++) {
#pragma unroll
    for (int cb = 0; cb < 8; cb++) {
      bf16x8 v8 = *(const bf16x8*)(h5 + ((size_t)pos * Bc + b) * 64 + cb * 8);
#pragma unroll
      for (int j = 0; j < 8; j++) {
        float v = bf2f((unsigned short)v8[j]);
        int f = (cb * 8 + j) * 9 + pos;
        l0 = fmaf(v, hw[f], l0);
        l1 = fmaf(v, hw[584 + f], l1);
      }
    }
  }
#pragma unroll
  for (int k = 0; k < 8; k++) {
    float v = info[(size_t)(bstart + b) * 8 + k];
    l0 = fmaf(v, hw[576 + k], l0);
    l1 = fmaf(v, hw[584 + 576 + k], l1);
  }
  float m = fmaxf(l0, l1);
  float e0 = __expf(l0 - m), e1 = __expf(l1 - m);
  float s = e0 + e1;
  out[(size_t)(bstart + b) * 2 + 0] = e0 / s;
  out[(size_t)(bstart + b) * 2 + 1] = e1 / s;
}

// ---------------------------------------------------------------------------

extern "C" void kernel_launch(void* const* d_in, const int* in_sizes, int n_in,
                              void* d_out, int out_size, void* d_ws, size_t ws_size,
                              hipStream_t stream) {
  const float* x = (const float*)d_in[0];
  const float* info = (const float*)d_in[1];
  const float* w1 = (const float*)d_in[2];
  const float* b1 = (const float*)d_in[3];
  const float* w2a = (const float*)d_in[4];
  const float* b2a = (const float*)d_in[5];
  const float* w2b = (const float*)d_in[6];
  const float* b2b = (const float*)d_in[7];
  const float* lw3 = (const float*)d_in[8];
  const float* lb3 = (const float*)d_in[9];
  const float* lw4 = (const float*)d_in[10];
  const float* lb4 = (const float*)d_in[11];
  const float* lw5 = (const float*)d_in[12];
  const float* lb5 = (const float*)d_in[13];
  const float* hw = (const float*)d_in[14];
  const float* hb = (const float*)d_in[15];
  float* out = (float*)d_out;

  const int B = in_sizes[0] / 18000;  // 2048

  // packed weights at ws start
  const size_t SZ2A = 9ull * 2048, SZ2B = 18ull * 2048, SZ3 = 81ull * 50 * 2048,
               SZ4 = 25ull * 50 * 2048, SZ5 = 9ull * 18 * 2048;
  unsigned short* wp2a = (unsigned short*)d_ws;
  unsigned short* wp2b = wp2a + SZ2A;
  unsigned short* wp3 = wp2b + SZ2B;
  unsigned short* wp4 = wp3 + SZ3;
  unsigned short* wp5 = wp4 + SZ4;
  size_t wp_bytes = (SZ2A + SZ2B + SZ3 + SZ4 + SZ5) * 2;
  wp_bytes = (wp_bytes + 255) & ~(size_t)255;
  float* w1t = (float*)((char*)d_ws + wp_bytes);  // 45*32 fp32
  size_t w1t_bytes = ((45 * 32 * 4) + 255) & ~(size_t)255;

  // per-sample chunk buffers: bufA bf16 53824B, bufB bf16 93312B
  const size_t per_sample = 53824 + 93312;
  int Bc = B;
  while (Bc > 256 && wp_bytes + w1t_bytes + (size_t)Bc * per_sample + 4096 > ws_size)
    Bc >>= 1;

  unsigned short* bufA = (unsigned short*)((char*)d_ws + wp_bytes + w1t_bytes);
  unsigned short* bufB =
      (unsigned short*)((char*)d_ws + wp_bytes + w1t_bytes + (size_t)Bc * 53824);

  // one-time weight packing (deterministic each launch)
  hipLaunchKernelGGL(pack_w1t, dim3(6), dim3(THREADS), 0, stream, w1, w1t);
  hipLaunchKernelGGL((pack_w<32, 3>), dim3((SZ2A + 255) / 256), dim3(THREADS), 0, stream,
                     w2a, wp2a, 1);
  hipLaunchKernelGGL((pack_w<64, 3>), dim3((SZ2B + 255) / 256), dim3(THREADS), 0, stream,
                     w2b, wp2b, 1);
  hipLaunchKernelGGL((pack_w<64, 5>), dim3((SZ3 + 255) / 256), dim3(THREADS), 0, stream,
                     lw3, wp3, 81);
  hipLaunchKernelGGL((pack_w<64, 5>), dim3((SZ4 + 255) / 256), dim3(THREADS), 0, stream,
                     lw4, wp4, 25);
  hipLaunchKernelGGL((pack_w<64, 3>), dim3((SZ5 + 255) / 256), dim3(THREADS), 0, stream,
                     lw5, wp5, 9);

  const int nchunks = B / Bc;
  for (int c = 0; c < nchunks; c++) {
    const int bstart = c * Bc;

    // conv1 fused: 5->32, 60x60 -> 29x29, k3 s2; 4 blocks/sample
    hipLaunchKernelGGL(conv1_direct, dim3(Bc * 4), dim3(256), 0, stream, x, w1t, b1,
                       bufA, Bc, bstart);
    // conv2a: 32->64, 29x29 -> 27x27, k3 s1 (BT=256)
    hipLaunchKernelGGL((conv_mfma<32, 29, 29, 27, 27, 3, 1, false, 256>),
                       dim3(729 * (Bc / 256)), dim3(256), 0, stream, bufA, wp2a, b2a,
                       bufB, Bc);
    // conv2b: 64->64, 27x27 -> 13x13, k3 s2 (BT=256)
    hipLaunchKernelGGL((conv_mfma<64, 27, 27, 13, 13, 3, 2, false, 256>),
                       dim3(169 * (Bc / 256)), dim3(256), 0, stream, bufB, wp2b, b2b,
                       bufA, Bc);
    // local3: 64->64, 13x13 -> 9x9, k5 (BT=256; weight re-fetch amortized)
    hipLaunchKernelGGL((conv_mfma<64, 13, 13, 9, 9, 5, 1, true, 256>),
                       dim3(81 * (Bc / 256)), dim3(256), 0, stream, bufA, wp3, lb3, bufB,
                       Bc);
    // local4: 64->64, 9x9 -> 5x5, k5 (BT=128; 2x blocks)
    hipLaunchKernelGGL((conv_mfma<64, 9, 9, 5, 5, 5, 1, true, 128>),
                       dim3(25 * (Bc / 128)), dim3(256), 0, stream, bufB, wp4, lb4, bufA,
                       Bc);
    // local5: 64->64, 5x5 -> 3x3, k3 (BT=64; 4x blocks)
    hipLaunchKernelGGL((conv_mfma<64, 5, 5, 3, 3, 3, 1, true, 64>),
                       dim3(9 * (Bc / 64)), dim3(256), 0, stream, bufA, wp5, lb5, bufB,
                       Bc);
    // head
    hipLaunchKernelGGL(head_k, dim3((Bc + THREADS - 1) / THREADS), dim3(THREADS), 0,
                       stream, bufB, info, hw, hb, out, Bc, bstart);
  }
}

// Round 8
// 566.953 us; speedup vs baseline: 1.5086x; 1.0131x over previous
//
#include <hip/hip_runtime.h>
#include <stdint.h>

#define THREADS 256

typedef short bf16x8 __attribute__((ext_vector_type(8)));
typedef float f32x4 __attribute__((ext_vector_type(4)));
typedef unsigned uint2_ __attribute__((ext_vector_type(2)));
typedef unsigned short ushort4_ __attribute__((ext_vector_type(4)));

#define GPTR(x) ((const __attribute__((address_space(1))) void*)(x))
#define LPTR(x) ((__attribute__((address_space(3))) void*)(x))

__device__ __forceinline__ unsigned short f2bf(float v) {
  unsigned u = __builtin_bit_cast(unsigned, v);
  u = (u + 0x7fff + ((u >> 16) & 1)) >> 16;
  return (unsigned short)u;
}
__device__ __forceinline__ float bf2f(unsigned short h) {
  return __builtin_bit_cast(float, (unsigned)h << 16);
}
__device__ __forceinline__ float fast_tanh(float x) {
  return 1.f - 2.f / (__expf(2.f * x) + 1.f);
}

// ---------------------------------------------------------------------------
// w1 transpose: (32, 45) -> (45, 32) fp32, for wave-uniform scalar loads.
// ---------------------------------------------------------------------------
__global__ void pack_w1t(const float* __restrict__ w1, float* __restrict__ w1t) {
  int idx = blockIdx.x * THREADS + threadIdx.x;
  if (idx >= 45 * 32) return;
  int t = idx >> 5, co = idx & 31;
  w1t[t * 32 + co] = w1[co * 45 + t];
}

// ---------------------------------------------------------------------------
// conv1 fused: x NCHW f32 -> out (29*29, Bc, 32) bf16, k3 s2, tanh.
// Block = 2 oh-rows of one sample (LDS 6KB f32). Wave = co-octet (weights
// wave-uniform -> s_load), lane = position, acc[8] in VGPRs.
// Per tap: 1 ds_read_b32 + 8 v_fmac (sgpr weight). Nothing to spill.
// ---------------------------------------------------------------------------
__global__ void __launch_bounds__(256) conv1_direct(
    const float* __restrict__ x, const float* __restrict__ w1t,
    const float* __restrict__ bias, unsigned short* __restrict__ out, int Bc,
    int bstart) {
  constexpr int CI = 5, CO = 32, IH = 60, IW = 60, OH = 29, OW = 29;
  constexpr int RPB = 2, NRB = 15;  // oh-rows per block, blocks per sample

  __shared__ float xs[CI * 5 * 60];  // 6000 B

  const int tid = threadIdx.x;
  const int b = blockIdx.x / NRB;
  const int qb = blockIdx.x % NRB;
  const int oh0 = qb * RPB;
  const int rows = min(RPB, OH - oh0);  // 2 (last block: 1)
  const int ih0 = oh0 * 2;
  const int ihn = rows * 2 + 1;  // 5 or 3

  const float* xp = x + (size_t)(bstart + b) * (CI * IH * IW);

  const int nf4 = CI * ihn * 15;
  for (int i = tid; i < nf4; i += 256) {
    int col = i % 15;
    int row = i / 15;  // ci*ihn + r
    int ci = row / ihn, r = row % ihn;
    ((float4*)xs)[row * 15 + col] = ((const float4*)xp)[(ci * IH + ih0 + r) * 15 + col];
  }
  __syncthreads();

  const int lane = tid & 63;
  const int wu = __builtin_amdgcn_readfirstlane(tid >> 6);  // co-octet
  if (lane >= rows * OW) return;
  const int r = lane / OW, c = lane % OW;
  const int base = (r * 2) * 60 + c * 2;
  const int cstr = ihn * 60;

  float acc[8];
#pragma unroll
  for (int j = 0; j < 8; j++) acc[j] = bias[wu * 8 + j];

#pragma unroll
  for (int ci = 0; ci < CI; ci++)
#pragma unroll
    for (int kh = 0; kh < 3; kh++)
#pragma unroll
      for (int kw = 0; kw < 3; kw++) {
        const float v = xs[ci * cstr + base + kh * 60 + kw];
        const float* wt = w1t + ((ci * 3 + kh) * 3 + kw) * 32 + wu * 8;
#pragma unroll
        for (int j = 0; j < 8; j++) acc[j] = fmaf(v, wt[j], acc[j]);
      }

  const int p = (oh0 + r) * OW + c;
  bf16x8 o;
#pragma unroll
  for (int j = 0; j < 8; j++) o[j] = (short)f2bf(fast_tanh(acc[j]));
  *(bf16x8*)(out + ((size_t)p * Bc + b) * CO + wu * 8) = o;
}

// ---------------------------------------------------------------------------
// Weight pre-pack into MFMA A-fragment order (bf16).
// dst wp: flat[pos][s][mt][lane][e], value = W[co=mt*16+(lane&15)]
//                                          [k = s*32 + (lane>>4)*8 + e]
// k-order: k = (kh*KS+kw)*CI + ci  (ci innermost).
// ---------------------------------------------------------------------------
template <int CI, int KS>
__global__ void __launch_bounds__(THREADS) pack_w(const float* __restrict__ w,
                                                  unsigned short* __restrict__ wp,
                                                  int npos) {
  constexpr int K = CI * KS * KS;
  constexpr int S = K / 32;
  int idx = blockIdx.x * THREADS + threadIdx.x;
  int total = npos * S * 2048;
  if (idx >= total) return;
  int e = idx & 7;
  int lane = (idx >> 3) & 63;
  int mt = (idx >> 9) & 3;
  int rest = idx >> 11;  // pos*S + s
  int s = rest % S, pos = rest / S;
  int co = mt * 16 + (lane & 15);
  int k = s * 32 + (lane >> 4) * 8 + e;
  int tap = k / CI, ci = k % CI;
  int kh = tap / KS, kw = tap % KS;
  float v = w[((((size_t)pos * 64 + co) * CI + ci) * KS + kh) * KS + kw];
  wp[idx] = f2bf(v);
}

// ---------------------------------------------------------------------------
// MFMA conv v3: bf16 in/out, fp32 accum, tanh. Batch-tile BT templated.
// X: (IH*IW, Bc, CI)  Wp: packed  Y: (OH*OW, Bc, 64)
// Block: 4 waves = one pos x 64 co x BT batch. BT=256 -> waves split batch;
// BT<256 -> waves also split co (more blocks for small layers).
// A double-buffered in LDS via global_load_lds; B direct 16B global loads.
// ---------------------------------------------------------------------------
template <int CI, int IH, int IW, int OH, int OW, int KS, int ST, bool LOCAL, int BT>
__global__ void __launch_bounds__(256) conv_mfma(
    const unsigned short* __restrict__ X, const unsigned short* __restrict__ Wp,
    const float* __restrict__ bias, unsigned short* __restrict__ Y, int Bc) {
  constexpr int S = CI * KS * KS / 32;
  constexpr int NPOS = OH * OW;
  constexpr int BW = BT / 64;  // waves along batch
  constexpr int CW = 4 / BW;   // waves along co
  constexpr int MT = 4 / CW;   // 16-co tiles per wave

  __shared__ unsigned short aT[2][2048];  // 8 KB double buffer

  const int tid = threadIdx.x;
  const int lane = tid & 63;
  const int wu = tid >> 6;
  const int n = lane & 15, g = lane >> 4;
  const int bw = wu % BW, cw = wu / BW;

  // bijective XCD-chunked swizzle (m204)
  int wg = blockIdx.x;
  {
    const int nwg = gridDim.x;
    const int q = nwg >> 3, rr = nwg & 7;
    const int xcd = wg & 7, l = wg >> 3;
    wg = (xcd < rr ? xcd * (q + 1) : rr * (q + 1) + (xcd - rr) * q) + l;
  }
  const int pos = wg % NPOS;
  const int btile = wg / NPOS;
  const int oh = pos / OW, ow = pos % OW;
  const int b0 = btile * BT + bw * 64;

  const unsigned short* Wpp = Wp + (LOCAL ? (size_t)pos * (S * 2048) : 0);

  f32x4 acc[MT][4] = {};

  const int bA = b0 + n;

  __builtin_amdgcn_global_load_lds(GPTR(Wpp + tid * 8), LPTR(&aT[0][tid * 8]), 16, 0, 0);

  int buf = 0;
  for (int s = 0; s < S; s++) {
    __syncthreads();
    if (s + 1 < S)
      __builtin_amdgcn_global_load_lds(GPTR(Wpp + (s + 1) * 2048 + tid * 8),
                                       LPTR(&aT[buf ^ 1][tid * 8]), 16, 0, 0);

    const int tap = (s * 32) / CI;
    const int ci0 = (s * 32) % CI + g * 8;
    const int kh = tap / KS, kw = tap % KS;
    const int pin = (oh * ST + kh) * IW + (ow * ST + kw);
    const unsigned short* xb = X + ((size_t)pin * Bc + bA) * CI + ci0;

    bf16x8 bfr[4];
#pragma unroll
    for (int j = 0; j < 4; j++) bfr[j] = *(const bf16x8*)(xb + j * 16 * CI);

    bf16x8 af[MT];
#pragma unroll
    for (int mt = 0; mt < MT; mt++)
      af[mt] = *(const bf16x8*)(&aT[buf][((cw * MT + mt) * 64 + lane) * 8]);

#pragma unroll
    for (int mt = 0; mt < MT; mt++)
#pragma unroll
      for (int j = 0; j < 4; j++)
        acc[mt][j] =
            __builtin_amdgcn_mfma_f32_16x16x32_bf16(af[mt], bfr[j], acc[mt][j], 0, 0, 0);
    buf ^= 1;
  }

  // epilogue: D col=lane&15 (batch), row=(lane>>4)*4+reg (co)
#pragma unroll
  for (int mt = 0; mt < MT; mt++) {
#pragma unroll
    for (int j = 0; j < 4; j++) {
      unsigned short o[4];
#pragma unroll
      for (int r = 0; r < 4; r++) {
        const int co = (cw * MT + mt) * 16 + g * 4 + r;
        const float bv = LOCAL ? bias[pos * 64 + co] : bias[co];
        o[r] = f2bf(fast_tanh(acc[mt][j][r] + bv));
      }
      const int b = b0 + j * 16 + n;
      uint2_ pk;
      pk[0] = (unsigned)o[0] | ((unsigned)o[1] << 16);
      pk[1] = (unsigned)o[2] | ((unsigned)o[3] << 16);
      *(uint2_*)(Y + ((size_t)pos * Bc + b) * 64 + (cw * MT + mt) * 16 + g * 4) = pk;
    }
  }
}

// ---------------------------------------------------------------------------
// Head: h5 (9, Bc, 64) bf16; f = co*9 + pos. concat info(8), linear, softmax.
// ---------------------------------------------------------------------------
__global__ void head_k(const unsigned short* __restrict__ h5,
                       const float* __restrict__ info, const float* __restrict__ hw,
                       const float* __restrict__ hb, float* __restrict__ out, int Bc,
                       int bstart) {
  int b = blockIdx.x * THREADS + threadIdx.x;
  if (b >= Bc) return;
  float l0 = hb[0], l1 = hb[1];
  for (int pos = 0; pos < 9; pos++) {
#pragma unroll
    for (int cb = 0; cb < 8; cb++) {
      bf16x8 v8 = *(const bf16x8*)(h5 + ((size_t)pos * Bc + b) * 64 + cb * 8);
#pragma unroll
      for (int j = 0; j < 8; j++) {
        float v = bf2f((unsigned short)v8[j]);
        int f = (cb * 8 + j) * 9 + pos;
        l0 = fmaf(v, hw[f], l0);
        l1 = fmaf(v, hw[584 + f], l1);
      }
    }
  }
#pragma unroll
  for (int k = 0; k < 8; k++) {
    float v = info[(size_t)(bstart + b) * 8 + k];
    l0 = fmaf(v, hw[576 + k], l0);
    l1 = fmaf(v, hw[584 + 576 + k], l1);
  }
  float m = fmaxf(l0, l1);
  float e0 = __expf(l0 - m), e1 = __expf(l1 - m);
  float s = e0 + e1;
  out[(size_t)(bstart + b) * 2 + 0] = e0 / s;
  out[(size_t)(bstart + b) * 2 + 1] = e1 / s;
}

// ---------------------------------------------------------------------------

extern "C" void kernel_launch(void* const* d_in, const int* in_sizes, int n_in,
                              void* d_out, int out_size, void* d_ws, size_t ws_size,
                              hipStream_t stream) {
  const float* x = (const float*)d_in[0];
  const float* info = (const float*)d_in[1];
  const float* w1 = (const float*)d_in[2];
  const float* b1 = (const float*)d_in[3];
  const float* w2a = (const float*)d_in[4];
  const float* b2a = (const float*)d_in[5];
  const float* w2b = (const float*)d_in[6];
  const float* b2b = (const float*)d_in[7];
  const float* lw3 = (const float*)d_in[8];
  const float* lb3 = (const float*)d_in[9];
  const float* lw4 = (const float*)d_in[10];
  const float* lb4 = (const float*)d_in[11];
  const float* lw5 = (const float*)d_in[12];
  const float* lb5 = (const float*)d_in[13];
  const float* hw = (const float*)d_in[14];
  const float* hb = (const float*)d_in[15];
  float* out = (float*)d_out;

  const int B = in_sizes[0] / 18000;  // 2048

  // packed weights at ws start
  const size_t SZ2A = 9ull * 2048, SZ2B = 18ull * 2048, SZ3 = 81ull * 50 * 2048,
               SZ4 = 25ull * 50 * 2048, SZ5 = 9ull * 18 * 2048;
  unsigned short* wp2a = (unsigned short*)d_ws;
  unsigned short* wp2b = wp2a + SZ2A;
  unsigned short* wp3 = wp2b + SZ2B;
  unsigned short* wp4 = wp3 + SZ3;
  unsigned short* wp5 = wp4 + SZ4;
  size_t wp_bytes = (SZ2A + SZ2B + SZ3 + SZ4 + SZ5) * 2;
  wp_bytes = (wp_bytes + 255) & ~(size_t)255;
  float* w1t = (float*)((char*)d_ws + wp_bytes);  // 45*32 fp32
  size_t w1t_bytes = ((45 * 32 * 4) + 255) & ~(size_t)255;

  // per-sample chunk buffers: bufA bf16 53824B, bufB bf16 93312B
  const size_t per_sample = 53824 + 93312;
  int Bc = B;
  while (Bc > 256 && wp_bytes + w1t_bytes + (size_t)Bc * per_sample + 4096 > ws_size)
    Bc >>= 1;

  unsigned short* bufA = (unsigned short*)((char*)d_ws + wp_bytes + w1t_bytes);
  unsigned short* bufB =
      (unsigned short*)((char*)d_ws + wp_bytes + w1t_bytes + (size_t)Bc * 53824);

  // one-time weight packing (deterministic each launch)
  hipLaunchKernelGGL(pack_w1t, dim3(6), dim3(THREADS), 0, stream, w1, w1t);
  hipLaunchKernelGGL((pack_w<32, 3>), dim3((SZ2A + 255) / 256), dim3(THREADS), 0, stream,
                     w2a, wp2a, 1);
  hipLaunchKernelGGL((pack_w<64, 3>), dim3((SZ2B + 255) / 256), dim3(THREADS), 0, stream,
                     w2b, wp2b, 1);
  hipLaunchKernelGGL((pack_w<64, 5>), dim3((SZ3 + 255) / 256), dim3(THREADS), 0, stream,
                     lw3, wp3, 81);
  hipLaunchKernelGGL((pack_w<64, 5>), dim3((SZ4 + 255) / 256), dim3(THREADS), 0, stream,
                     lw4, wp4, 25);
  hipLaunchKernelGGL((pack_w<64, 3>), dim3((SZ5 + 255) / 256), dim3(THREADS), 0, stream,
                     lw5, wp5, 9);

  const int nchunks = B / Bc;
  for (int c = 0; c < nchunks; c++) {
    const int bstart = c * Bc;

    // conv1 fused: 5->32, 60x60 -> 29x29, k3 s2; 15 blocks/sample (2 oh-rows)
    hipLaunchKernelGGL(conv1_direct, dim3(Bc * 15), dim3(256), 0, stream, x, w1t, b1,
                       bufA, Bc, bstart);
    // conv2a: 32->64, 29x29 -> 27x27, k3 s1 (BT=256)
    hipLaunchKernelGGL((conv_mfma<32, 29, 29, 27, 27, 3, 1, false, 256>),
                       dim3(729 * (Bc / 256)), dim3(256), 0, stream, bufA, wp2a, b2a,
                       bufB, Bc);
    // conv2b: 64->64, 27x27 -> 13x13, k3 s2 (BT=256)
    hipLaunchKernelGGL((conv_mfma<64, 27, 27, 13, 13, 3, 2, false, 256>),
                       dim3(169 * (Bc / 256)), dim3(256), 0, stream, bufB, wp2b, b2b,
                       bufA, Bc);
    // local3: 64->64, 13x13 -> 9x9, k5 (BT=256)
    hipLaunchKernelGGL((conv_mfma<64, 13, 13, 9, 9, 5, 1, true, 256>),
                       dim3(81 * (Bc / 256)), dim3(256), 0, stream, bufA, wp3, lb3, bufB,
                       Bc);
    // local4: 64->64, 9x9 -> 5x5, k5 (BT=128)
    hipLaunchKernelGGL((conv_mfma<64, 9, 9, 5, 5, 5, 1, true, 128>),
                       dim3(25 * (Bc / 128)), dim3(256), 0, stream, bufB, wp4, lb4, bufA,
                       Bc);
    // local5: 64->64, 5x5 -> 3x3, k3 (BT=64)
    hipLaunchKernelGGL((conv_mfma<64, 5, 5, 3, 3, 3, 1, true, 64>),
                       dim3(9 * (Bc / 64)), dim3(256), 0, stream, bufA, wp5, lb5, bufB,
                       Bc);
    // head
    hipLaunchKernelGGL(head_k, dim3((Bc + THREADS - 1) / THREADS), dim3(THREADS), 0,
                       stream, bufB, info, hw, hb, out, Bc, bstart);
  }
}